// Round 5
// baseline (6491.119 us; speedup 1.0000x reference)
//
#include <hip/hip_runtime.h>

#define LOWV (-10000.0f)
#define NBLK 256
typedef unsigned long long u64;

__device__ __forceinline__ float sigf(float x){ return 1.0f/(1.0f+expf(-x)); }
__device__ __forceinline__ unsigned fkey(float f){
    unsigned u = __float_as_uint(f);
    return (u & 0x80000000u) ? ~u : (u | 0x80000000u);
}
__device__ __forceinline__ float funkey(unsigned k){
    unsigned u = (k & 0x80000000u) ? (k ^ 0x80000000u) : ~k;
    return __uint_as_float(u);
}

// ---------- Whx4[k*640+j] = float4 gates (i,f,g,o) of Wh[k][:] ; also zero cnt8 ----------
__global__ __launch_bounds__(256) void k_t0(const float* __restrict__ Wh, float4* __restrict__ Whx4,
                                            int* __restrict__ cnt8){
    if (blockIdx.x == 0 && threadIdx.x < 8) cnt8[threadIdx.x*16] = 0;
    int idx = blockIdx.x*256 + threadIdx.x;      // 640*640
    int k = idx / 640, j = idx - k*640;
    const float* row = Wh + (size_t)k*2560;
    Whx4[idx] = make_float4(row[j], row[640+j], row[1280+j], row[1920+j]);
}

// ---------- tiled transposes: WpredT[512][640], WoutT[1024][512], WencT[512][1024] ----------
__global__ __launch_bounds__(256) void k_tr(const float* __restrict__ Wpred,
        const float* __restrict__ Wout, const float* __restrict__ Wenc,
        float* __restrict__ WpredT, float* __restrict__ WoutT, float* __restrict__ WencT){
    __shared__ float t[64][65];
    int b = blockIdx.x;
    const float* in; float* outp; int R, C, tr, tc;
    if (b < 80)      { in=Wpred; outp=WpredT; R=640;  C=512;  tr=b/8;        tc=b%8; }
    else if (b < 208){ in=Wout;  outp=WoutT;  R=512;  C=1024; tr=(b-80)/16;  tc=(b-80)%16; }
    else             { in=Wenc;  outp=WencT;  R=1024; C=512;  tr=(b-208)/8;  tc=(b-208)%8; }
    int tx = threadIdx.x & 63, ty0 = threadIdx.x >> 6;
    #pragma unroll
    for (int i = 0; i < 16; ++i){
        int row = i*4 + ty0;
        t[row][tx] = in[(size_t)(tr*64 + row)*C + tc*64 + tx];
    }
    __syncthreads();
    #pragma unroll
    for (int i = 0; i < 16; ++i){
        int row = i*4 + ty0;
        outp[(size_t)(tc*64 + row)*R + tr*64 + tx] = t[tx][row];
    }
}

// ---------- EWi4[v*640+j] = float4 gates of E@Wi + bi + bh ----------
__global__ __launch_bounds__(256) void k_ewi(const float* __restrict__ E, const float* __restrict__ Wi,
        const float* __restrict__ bi, const float* __restrict__ bh, float4* __restrict__ EWi4){
    int tid = threadIdx.x, lane = tid & 63, wvv = tid >> 6;
    int vb = blockIdx.x / 10, jb = blockIdx.x % 10;   // 1280 blocks
    int j = jb*64 + lane;
    int v0 = vb*8 + wvv*2;
    float acc[2][4];
    #pragma unroll
    for (int i=0;i<2;++i)
        #pragma unroll
        for (int g=0;g<4;++g) acc[i][g] = 0.f;
    for (int k0 = 0; k0 < 512; k0 += 4){
        float ev[2][4];
        #pragma unroll
        for (int i=0;i<2;++i) *(float4*)ev[i] = *(const float4*)(E + (size_t)(v0+i)*512 + k0);
        #pragma unroll
        for (int kk=0;kk<4;++kk){
            const float* wr = Wi + (size_t)(k0+kk)*2560 + j;
            float w0 = wr[0], w1 = wr[640], w2 = wr[1280], w3 = wr[1920];
            #pragma unroll
            for (int i=0;i<2;++i){
                acc[i][0] += ev[i][kk]*w0; acc[i][1] += ev[i][kk]*w1;
                acc[i][2] += ev[i][kk]*w2; acc[i][3] += ev[i][kk]*w3;
            }
        }
    }
    float b0 = bi[j] + bh[j], b1 = bi[640+j] + bh[640+j];
    float b2 = bi[1280+j] + bh[1280+j], b3 = bi[1920+j] + bh[1920+j];
    #pragma unroll
    for (int i=0;i<2;++i)
        EWi4[(size_t)(v0+i)*640 + j] = make_float4(acc[i][0]+b0, acc[i][1]+b1, acc[i][2]+b2, acc[i][3]+b3);
}

// ---------- persistent decode kernel ----------
__global__ __launch_bounds__(512) void mega(
    const float* __restrict__ enc, const int* __restrict__ lens, const float* __restrict__ bj,
    const float* __restrict__ WpredT, const float* __restrict__ WoutT, const float* __restrict__ WencT,
    const float4* __restrict__ Whx4, const float4* __restrict__ EWi4,
    float* __restrict__ hT, float* __restrict__ encPT, float* __restrict__ jointT,
    u64* __restrict__ packed16, float* __restrict__ sumexp16,
    int* __restrict__ actA, int* __restrict__ encTA, int* __restrict__ nEmA,
    float* __restrict__ scoresA, int* __restrict__ cnt8, float* __restrict__ out)
{
    __shared__ float sA[1280];      // WpredT 2 cols
    __shared__ float4 sB4[512];     // Wout 4 cols packed per k
    __shared__ float sR[10240];     // LSTM blocks: Whx4 [jj][k] (float4) | enc blocks: WencT 8 cols
    __shared__ float sXA[512];      // joint partials / P3 enc flags
    __shared__ float sP[2048];      // P2 partials [kq][c][r]
    __shared__ u64   sKX[512];
    __shared__ float sEX[512];
    __shared__ float sBJ[2];

    const int bid = blockIdx.x, tid = threadIdx.x, lane = tid & 63, wv = tid >> 6;
    int ep = 0;
    float creg = 0.f;

    auto gsync = [&](bool inv){
        __syncthreads();
        if (tid == 0){
            __builtin_amdgcn_fence(__ATOMIC_RELEASE, "agent");
            __hip_atomic_fetch_add(&cnt8[(bid & 7)*16], 1, __ATOMIC_RELAXED, __HIP_MEMORY_SCOPE_AGENT);
            ++ep;
            for (;;){
                int sum = 0;
                #pragma unroll
                for (int i = 0; i < 8; ++i)
                    sum += __hip_atomic_load(&cnt8[i*16], __ATOMIC_RELAXED, __HIP_MEMORY_SCOPE_AGENT);
                if (sum >= ep*NBLK) break;
                __builtin_amdgcn_s_sleep(4);
            }
        }
        __syncthreads();
        if (inv) __builtin_amdgcn_fence(__ATOMIC_ACQUIRE, "agent");
    };

    // ---- persistent weight staging ----
    for (int i = tid; i < 1280; i += 512) sA[i] = WpredT[(size_t)bid*1280 + i];
    for (int i = tid; i < 2048; i += 512){
        int c = i >> 9, k = i & 511;
        ((float*)sB4)[k*4 + c] = WoutT[(size_t)(bid*4 + c)*512 + k];
    }
    if (bid < 160){
        float4* sR4 = (float4*)sR;
        for (int i = tid; i < 2560; i += 512){
            int jj = i / 640, k = i - jj*640;
            sR4[i] = Whx4[(size_t)k*640 + bid*4 + jj];
        }
    } else if (bid < 224){
        for (int i = tid; i < 8192; i += 512) sR[i] = WencT[(size_t)(bid-160)*8192 + i];
    }
    if (tid < 2) sBJ[tid] = bj[bid*2 + tid];
    __syncthreads();

    // ---- prologue ----
    {
        int gidx = bid*512 + tid;
        if (gidx < 48*16*128){ packed16[gidx] = 0ull; sumexp16[gidx] = 0.f; }
    }
    if (bid < 160){
        int jj = wv >> 1, rh = wv & 1;
        int r = rh*64 + lane, j = bid*4 + jj;
        float4 e0 = EWi4[j];
        float c0v = sigf(e0.x)*tanhf(e0.z);
        creg = c0v;
        hT[(size_t)j*128 + r] = tanhf(c0v)*sigf(e0.w);
    } else if (bid < 224){
        int cg0 = (bid-160)*8;
        for (int r = wv; r < 128; r += 8){
            const float* er = enc + (size_t)r*160*1024;   // frame 0
            float a[8] = {0,0,0,0,0,0,0,0};
            #pragma unroll
            for (int c4 = 0; c4 < 4; ++c4){
                int k = c4*256 + lane*4;
                float4 ev = *(const float4*)(er + k);
                #pragma unroll
                for (int cc = 0; cc < 8; ++cc){
                    float4 w4 = *(const float4*)(sR + cc*1024 + k);
                    a[cc] += ev.x*w4.x + ev.y*w4.y + ev.z*w4.z + ev.w*w4.w;
                }
            }
            #pragma unroll
            for (int cc = 0; cc < 8; ++cc){
                #pragma unroll
                for (int off = 32; off; off >>= 1) a[cc] += __shfl_xor(a[cc], off, 64);
            }
            if (lane == 0){
                #pragma unroll
                for (int cc = 0; cc < 8; ++cc) encPT[(size_t)(cg0+cc)*128 + r] = a[cc];
            }
        }
    } else if (bid == 255){
        if (tid < 128){ actA[tid] = 1; encTA[tid] = 0; nEmA[tid] = 0; scoresA[tid] = 0.f; }
    }
    gsync(true);

    for (int s = 0; s < 48; ++s){
        const int p = s & 1, w = 1 - p;
        const float* hp = hT + (size_t)p*81920;
        float ai=0.f, af=0.f, ag=0.f, ao=0.f;   // LSTM gates live P1 -> P3 in registers

        // ================= P1: joint (+ fused LSTM pre-gates for blocks<160) =================
        if (bid < 160){
            int jj = wv >> 1, rh = wv & 1;
            int r = rh*64 + lane;
            const float* hc = hp + r;
            const float4* w4p = ((const float4*)sR) + jj*640;
            float hh[16], hn[16];
            #pragma unroll
            for (int kk=0;kk<16;++kk) hh[kk] = hc[(size_t)kk*128];
            if (jj < 2){
                const float* wj = sA + jj*640;
                float aj = 0.f;
                for (int k0 = 0; k0 < 640; k0 += 16){
                    if (k0 < 624){
                        const float* hcn = hc + (size_t)(k0+16)*128;
                        #pragma unroll
                        for (int kk=0;kk<16;++kk) hn[kk] = hcn[(size_t)kk*128];
                    }
                    #pragma unroll
                    for (int kk=0;kk<16;++kk){
                        float h = hh[kk];
                        float4 w4 = w4p[k0+kk];
                        ai += h*w4.x; af += h*w4.y; ag += h*w4.z; ao += h*w4.w;
                        aj += h*wj[k0+kk];
                    }
                    if (k0 < 624){
                        #pragma unroll
                        for (int kk=0;kk<16;++kk) hh[kk] = hn[kk];
                    }
                }
                int cg = bid*2 + jj;
                float v = aj + encPT[(size_t)cg*128 + r] + sBJ[jj];
                jointT[(size_t)cg*128 + r] = tanhf(v);
            } else {
                for (int k0 = 0; k0 < 640; k0 += 16){
                    if (k0 < 624){
                        const float* hcn = hc + (size_t)(k0+16)*128;
                        #pragma unroll
                        for (int kk=0;kk<16;++kk) hn[kk] = hcn[(size_t)kk*128];
                    }
                    #pragma unroll
                    for (int kk=0;kk<16;++kk){
                        float h = hh[kk];
                        float4 w4 = w4p[k0+kk];
                        ai += h*w4.x; af += h*w4.y; ag += h*w4.z; ao += h*w4.w;
                    }
                    if (k0 < 624){
                        #pragma unroll
                        for (int kk=0;kk<16;++kk) hh[kk] = hn[kk];
                    }
                }
            }
        } else {
            int c = wv & 1, rh = (wv >> 1) & 1, kh = wv >> 2;
            int r = rh*64 + lane;
            const float* wr = sA + c*640 + kh*320;
            const float* hc = hp + (size_t)(kh*320)*128 + r;
            float acc = 0.f;
            #pragma unroll 16
            for (int k = 0; k < 320; ++k) acc += hc[(size_t)k*128] * wr[k];
            sXA[wv*64 + lane] = acc;
            __syncthreads();
            if (tid < 256){
                int c2 = wv & 1, rh2 = wv >> 1;
                int r2 = rh2*64 + lane;
                int cg = bid*2 + c2;
                float v = sXA[(c2 + rh2*2)*64 + lane] + sXA[(c2 + rh2*2 + 4)*64 + lane]
                        + encPT[(size_t)cg*128 + r2] + sBJ[c2];
                jointT[(size_t)cg*128 + r2] = tanhf(v);
            }
        }
        gsync(false);

        // ================= P2: logits + argmax/sumexp (16-slot atomics) =================
        {
            int kq = wv >> 1, rh = wv & 1;
            int r = rh*64 + lane;
            const float* jc = jointT + (size_t)(kq*128)*128 + r;
            const float4* wb = sB4 + kq*128;
            float a0=0.f, a1=0.f, a2=0.f, a3=0.f;
            float jh[16], jn[16];
            #pragma unroll
            for (int kk=0;kk<16;++kk) jh[kk] = jc[(size_t)kk*128];
            for (int k0 = 0; k0 < 128; k0 += 16){
                if (k0 < 112){
                    const float* jcn = jc + (size_t)(k0+16)*128;
                    #pragma unroll
                    for (int kk=0;kk<16;++kk) jn[kk] = jcn[(size_t)kk*128];
                }
                #pragma unroll
                for (int kk=0;kk<16;++kk){
                    float jv = jh[kk];
                    float4 w4 = wb[k0+kk];
                    a0 += jv*w4.x; a1 += jv*w4.y; a2 += jv*w4.z; a3 += jv*w4.w;
                }
                if (k0 < 112){
                    #pragma unroll
                    for (int kk=0;kk<16;++kk) jh[kk] = jn[kk];
                }
            }
            sP[kq*512 + 0*128 + r] = a0;
            sP[kq*512 + 1*128 + r] = a1;
            sP[kq*512 + 2*128 + r] = a2;
            sP[kq*512 + 3*128 + r] = a3;
            __syncthreads();
            {
                int c = tid >> 7, rr = tid & 127;
                float lg = sP[c*128+rr] + sP[512 + c*128+rr] + sP[1024 + c*128+rr] + sP[1536 + c*128+rr];
                float ex = expf(lg);
                int col = bid*4 + c;
                bool force = nEmA[p*128 + rr] >= 2;
                int idx; float va;
                if (col == 0){ idx = 1024; va = lg; }
                else { idx = col; va = force ? LOWV : lg; }
                u64 key = ((u64)fkey(va) << 32) | (unsigned)(2047 - idx);
                sKX[c*128 + rr] = key;
                sEX[c*128 + rr] = ex;
            }
            __syncthreads();
            if (tid < 128){
                u64 m = sKX[tid]; float es = sEX[tid];
                #pragma unroll
                for (int q = 1; q < 4; ++q){
                    u64 o = sKX[q*128 + tid]; if (o > m) m = o;
                    es += sEX[q*128 + tid];
                }
                int slot = bid >> 4;
                atomicMax(&packed16[((size_t)s*16 + slot)*128 + tid], m);
                atomicAdd(&sumexp16[((size_t)s*16 + slot)*128 + tid], es);
            }
        }
        gsync(false);

        // ================= P3: LSTM finalize | lazy encP | scalar state =================
        if (bid < 160){
            int jj = wv >> 1, rh = wv & 1;
            int r = rh*64 + lane, j = bid*4 + jj;
            u64 m = 0;
            #pragma unroll
            for (int q = 0; q < 16; ++q){
                u64 o = __hip_atomic_load(&packed16[((size_t)s*16 + q)*128 + r], __ATOMIC_RELAXED, __HIP_MEMORY_SCOPE_AGENT);
                if (o > m) m = o;
            }
            int tok = 2047 - (int)(unsigned)(m & 0xffffffffu);
            int act = actA[p*128 + r];
            bool upd = act && (tok != 1024);
            int tokc = tok < 1023 ? tok : 1023;
            float4 ew = EWi4[(size_t)tokc*640 + j];
            float h2;
            if (upd){
                float cn = sigf(af + ew.y)*creg + sigf(ai + ew.x)*tanhf(ag + ew.z);
                h2 = tanhf(cn)*sigf(ao + ew.w);
                creg = cn;
            } else {
                h2 = hp[(size_t)j*128 + r];
            }
            hT[(size_t)w*81920 + (size_t)j*128 + r] = h2;
        } else if (bid < 224){
            int* flags = (int*)sXA;
            if (tid < 128){
                u64 m = 0;
                #pragma unroll
                for (int q = 0; q < 16; ++q){
                    u64 o = __hip_atomic_load(&packed16[((size_t)s*16 + q)*128 + tid], __ATOMIC_RELAXED, __HIP_MEMORY_SCOPE_AGENT);
                    if (o > m) m = o;
                }
                int tok = 2047 - (int)(unsigned)(m & 0xffffffffu);
                int act = actA[p*128 + tid];
                int t = encTA[p*128 + tid] + 1; if (t > 159) t = 159;
                flags[tid] = (act && tok == 1024) ? t : -1;
            }
            __syncthreads();
            int cg0 = (bid-160)*8;
            for (int r = wv; r < 128; r += 8){
                int t = flags[r];
                if (t < 0) continue;
                const float* er = enc + ((size_t)r*160 + t)*1024;
                float a[8] = {0,0,0,0,0,0,0,0};
                #pragma unroll
                for (int c4 = 0; c4 < 4; ++c4){
                    int k = c4*256 + lane*4;
                    float4 ev = *(const float4*)(er + k);
                    #pragma unroll
                    for (int cc = 0; cc < 8; ++cc){
                        float4 w4 = *(const float4*)(sR + cc*1024 + k);
                        a[cc] += ev.x*w4.x + ev.y*w4.y + ev.z*w4.z + ev.w*w4.w;
                    }
                }
                #pragma unroll
                for (int cc = 0; cc < 8; ++cc){
                    #pragma unroll
                    for (int off = 32; off; off >>= 1) a[cc] += __shfl_xor(a[cc], off, 64);
                }
                if (lane == 0){
                    #pragma unroll
                    for (int cc = 0; cc < 8; ++cc) encPT[(size_t)(cg0+cc)*128 + r] = a[cc];
                }
            }
        } else if (bid == 255){
            if (tid < 128){
                int r = tid;
                u64 m = 0; float se = 0.f;
                #pragma unroll
                for (int q = 0; q < 16; ++q){
                    u64 o = __hip_atomic_load(&packed16[((size_t)s*16 + q)*128 + r], __ATOMIC_RELAXED, __HIP_MEMORY_SCOPE_AGENT);
                    if (o > m) m = o;
                    se += __hip_atomic_load(&sumexp16[((size_t)s*16 + q)*128 + r], __ATOMIC_RELAXED, __HIP_MEMORY_SCOPE_AGENT);
                }
                int act = actA[p*128 + r];
                int et  = encTA[p*128 + r];
                int ne  = nEmA[p*128 + r];
                float sc = scoresA[p*128 + r];
                int len = lens[r];
                int tok_out = 1024, act_n = 0;
                if (act){
                    int tok = 2047 - (int)(unsigned)(m & 0xffffffffu);
                    float chosen = funkey((unsigned)(m >> 32));
                    float tlp = chosen - logf(se);
                    int isb = (tok == 1024);
                    sc += tlp;
                    et += isb ? 1 : 0;
                    ne  = isb ? 0 : ne + 1;
                    act_n = (et < len) ? 1 : 0;
                    tok_out = (act_n || isb) ? tok : 1024;
                }
                actA[w*128 + r] = act_n;
                encTA[w*128 + r] = et;
                nEmA[w*128 + r] = ne;
                scoresA[w*128 + r] = sc;
                out[(size_t)r*48 + s] = (float)tok_out;
                if (s == 47) out[6144 + r] = sc;
            }
        }
        gsync(true);
    }
}

extern "C" void kernel_launch(void* const* d_in, const int* in_sizes, int n_in,
                              void* d_out, int out_size, void* d_ws, size_t ws_size,
                              hipStream_t stream) {
    const float* enc   = (const float*)d_in[0];
    const int*   lens  = (const int*)  d_in[1];
    const float* E     = (const float*)d_in[3];
    const float* Wi    = (const float*)d_in[4];
    const float* Wh    = (const float*)d_in[5];
    const float* bi    = (const float*)d_in[6];
    const float* bh    = (const float*)d_in[7];
    const float* Wenc  = (const float*)d_in[8];
    const float* Wpred = (const float*)d_in[9];
    const float* bj    = (const float*)d_in[10];
    const float* Wout  = (const float*)d_in[11];
    float* out = (float*)d_out;

    char* base = (char*)d_ws;
    size_t off = 0;
    auto carve = [&](size_t bytes) -> void* {
        void* pp = base + off;
        off += (bytes + 255) & ~(size_t)255;
        return pp;
    };
    float4* Whx4  = (float4*)carve((size_t)640*640*16);     // 6.55 MB
    float*  WpredT= (float*)carve((size_t)512*640*4);
    float*  WoutT = (float*)carve((size_t)1024*512*4);
    float*  WencT = (float*)carve((size_t)512*1024*4);
    float4* EWi4  = (float4*)carve((size_t)1024*640*16);    // 10.5 MB
    float*  hT    = (float*)carve((size_t)2*640*128*4);
    float*  encPT = (float*)carve((size_t)512*128*4);
    float*  jointT= (float*)carve((size_t)512*128*4);
    u64*    packed16 = (u64*)carve((size_t)48*16*128*8);
    float*  sumexp16 = (float*)carve((size_t)48*16*128*4);
    int*    actA  = (int*)carve(2*128*4);
    int*    encTA = (int*)carve(2*128*4);
    int*    nEmA  = (int*)carve(2*128*4);
    float*  scoresA = (float*)carve(2*128*4);
    int*    cnt8  = (int*)carve(8*16*4);
    (void)ws_size; (void)in_sizes; (void)n_in; (void)out_size;

    k_t0 <<<1600, 256, 0, stream>>>(Wh, Whx4, cnt8);
    k_tr <<<336,  256, 0, stream>>>(Wpred, Wout, Wenc, WpredT, WoutT, WencT);
    k_ewi<<<1280, 256, 0, stream>>>(E, Wi, bi, bh, EWi4);
    mega <<<NBLK, 512, 0, stream>>>(enc, lens, bj, WpredT, WoutT, WencT, Whx4, EWi4,
                                    hT, encPT, jointT, packed16, sumexp16,
                                    actA, encTA, nEmA, scoresA, cnt8, out);
}

// Round 6
// 3478.937 us; speedup vs baseline: 1.8658x; 1.8658x over previous
//
#include <hip/hip_runtime.h>

#define LOWV (-10000.0f)
#define NBLK 256
typedef unsigned long long u64;

__device__ __forceinline__ float sigf(float x){ return 1.0f/(1.0f+expf(-x)); }
__device__ __forceinline__ unsigned fkey(float f){
    unsigned u = __float_as_uint(f);
    return (u & 0x80000000u) ? ~u : (u | 0x80000000u);
}
__device__ __forceinline__ float funkey(unsigned k){
    unsigned u = (k & 0x80000000u) ? (k ^ 0x80000000u) : ~k;
    return __uint_as_float(u);
}

// ---------- Whx4[k*640+j] = float4 gates (i,f,g,o) of Wh[k][:]; zero barrier counters ----------
__global__ __launch_bounds__(256) void k_t0(const float* __restrict__ Wh, float4* __restrict__ Whx4,
                                            int* __restrict__ cnt32){
    if (blockIdx.x == 0 && threadIdx.x < 32) cnt32[threadIdx.x*16] = 0;
    int idx = blockIdx.x*256 + threadIdx.x;      // 640*640
    int k = idx / 640, j = idx - k*640;
    const float* row = Wh + (size_t)k*2560;
    Whx4[idx] = make_float4(row[j], row[640+j], row[1280+j], row[1920+j]);
}

// ---------- tiled transposes: WpredT[512][640], WoutT[1024][512], WencT[512][1024] ----------
__global__ __launch_bounds__(256) void k_tr(const float* __restrict__ Wpred,
        const float* __restrict__ Wout, const float* __restrict__ Wenc,
        float* __restrict__ WpredT, float* __restrict__ WoutT, float* __restrict__ WencT){
    __shared__ float t[64][65];
    int b = blockIdx.x;
    const float* in; float* outp; int R, C, tr, tc;
    if (b < 80)      { in=Wpred; outp=WpredT; R=640;  C=512;  tr=b/8;        tc=b%8; }
    else if (b < 208){ in=Wout;  outp=WoutT;  R=512;  C=1024; tr=(b-80)/16;  tc=(b-80)%16; }
    else             { in=Wenc;  outp=WencT;  R=1024; C=512;  tr=(b-208)/8;  tc=(b-208)%8; }
    int tx = threadIdx.x & 63, ty0 = threadIdx.x >> 6;
    #pragma unroll
    for (int i = 0; i < 16; ++i){
        int row = i*4 + ty0;
        t[row][tx] = in[(size_t)(tr*64 + row)*C + tc*64 + tx];
    }
    __syncthreads();
    #pragma unroll
    for (int i = 0; i < 16; ++i){
        int row = i*4 + ty0;
        outp[(size_t)(tc*64 + row)*R + tr*64 + tx] = t[tx][row];
    }
}

// ---------- EWi4[v*640+j] = float4 gates of E@Wi + bi + bh ----------
__global__ __launch_bounds__(256) void k_ewi(const float* __restrict__ E, const float* __restrict__ Wi,
        const float* __restrict__ bi, const float* __restrict__ bh, float4* __restrict__ EWi4){
    int tid = threadIdx.x, lane = tid & 63, wvv = tid >> 6;
    int vb = blockIdx.x / 10, jb = blockIdx.x % 10;   // 1280 blocks
    int j = jb*64 + lane;
    int v0 = vb*8 + wvv*2;
    float acc[2][4];
    #pragma unroll
    for (int i=0;i<2;++i)
        #pragma unroll
        for (int g=0;g<4;++g) acc[i][g] = 0.f;
    for (int k0 = 0; k0 < 512; k0 += 4){
        float ev[2][4];
        #pragma unroll
        for (int i=0;i<2;++i) *(float4*)ev[i] = *(const float4*)(E + (size_t)(v0+i)*512 + k0);
        #pragma unroll
        for (int kk=0;kk<4;++kk){
            const float* wr = Wi + (size_t)(k0+kk)*2560 + j;
            float w0 = wr[0], w1 = wr[640], w2 = wr[1280], w3 = wr[1920];
            #pragma unroll
            for (int i=0;i<2;++i){
                acc[i][0] += ev[i][kk]*w0; acc[i][1] += ev[i][kk]*w1;
                acc[i][2] += ev[i][kk]*w2; acc[i][3] += ev[i][kk]*w3;
            }
        }
    }
    float b0 = bi[j] + bh[j], b1 = bi[640+j] + bh[640+j];
    float b2 = bi[1280+j] + bh[1280+j], b3 = bi[1920+j] + bh[1920+j];
    #pragma unroll
    for (int i=0;i<2;++i)
        EWi4[(size_t)(v0+i)*640 + j] = make_float4(acc[i][0]+b0, acc[i][1]+b1, acc[i][2]+b2, acc[i][3]+b3);
}

// ---------- persistent decode kernel ----------
__global__ __launch_bounds__(512) void mega(
    const float* __restrict__ enc, const int* __restrict__ lens, const float* __restrict__ bj,
    const float* __restrict__ WpredT, const float* __restrict__ WoutT, const float* __restrict__ WencT,
    const float4* __restrict__ Whx4, const float4* __restrict__ EWi4,
    float* __restrict__ hT, float* __restrict__ encPT, float* __restrict__ jointT,
    u64* __restrict__ packed16, float* __restrict__ sumexp16,
    int* __restrict__ actA, int* __restrict__ encTA, int* __restrict__ nEmA,
    float* __restrict__ scoresA, int* __restrict__ tokF, int* __restrict__ advF,
    int* __restrict__ cnt32, float* __restrict__ out)
{
    __shared__ float sA[1280];      // WpredT 2 cols
    __shared__ float4 sB4[512];     // Wout 4 cols packed per k
    __shared__ float sR[10240];     // LSTM: Whx4 slice (float4[4][640]) | ENC: WencT 8 cols
    __shared__ float sXA[512];      // P1 joint partials
    __shared__ float sP[2048];      // P2 partials [kq][c][r]
    __shared__ u64   sKX[512];
    __shared__ float sEX[512];
    __shared__ float sBJ[2];

    const int bid = blockIdx.x, tid = threadIdx.x, lane = tid & 63, wv = tid >> 6;
    int ep = 0;
    float creg = 0.f;

    auto gsync = [&](bool inv){
        __syncthreads();
        ++ep;
        if (tid == 0){
            __builtin_amdgcn_fence(__ATOMIC_RELEASE, "agent");
            __hip_atomic_fetch_add(&cnt32[(bid & 31)*16], 1, __ATOMIC_RELAXED, __HIP_MEMORY_SCOPE_AGENT);
        }
        if (wv == 0){
            int target = ep * NBLK;
            for (;;){
                int v = (lane < 32) ? __hip_atomic_load(&cnt32[lane*16], __ATOMIC_RELAXED, __HIP_MEMORY_SCOPE_AGENT) : 0;
                #pragma unroll
                for (int off = 32; off; off >>= 1) v += __shfl_xor(v, off, 64);
                if (v >= target) break;
                __builtin_amdgcn_s_sleep(2);
            }
        }
        __syncthreads();
        if (inv) __builtin_amdgcn_fence(__ATOMIC_ACQUIRE, "agent");
    };

    // ---- persistent weight staging ----
    for (int i = tid; i < 1280; i += 512) sA[i] = WpredT[(size_t)bid*1280 + i];
    for (int i = tid; i < 2048; i += 512){
        int c = i >> 9, k = i & 511;
        ((float*)sB4)[k*4 + c] = WoutT[(size_t)(bid*4 + c)*512 + k];
    }
    if (bid < 160){
        float4* sR4 = (float4*)sR;
        for (int i = tid; i < 2560; i += 512){
            int jj = i / 640, k = i - jj*640;
            sR4[i] = Whx4[(size_t)k*640 + bid*4 + jj];
        }
    } else if (bid < 224){
        for (int i = tid; i < 8192; i += 512) sR[i] = WencT[(size_t)(bid-160)*8192 + i];
    }
    if (tid < 2) sBJ[tid] = bj[bid*2 + tid];
    __syncthreads();

    // ---- prologue ----
    {
        int gidx = bid*512 + tid;
        if (gidx < 48*16*128){ packed16[gidx] = 0ull; sumexp16[gidx] = 0.f; }
    }
    if (bid < 160){
        int jj = wv >> 1, rh = wv & 1;
        int r = rh*64 + lane, j = bid*4 + jj;
        float4 e0 = EWi4[j];
        float c0v = sigf(e0.x)*tanhf(e0.z);
        creg = c0v;
        hT[(size_t)j*128 + r] = tanhf(c0v)*sigf(e0.w);
    } else if (bid < 224){
        int cg0 = (bid-160)*8;
        for (int r = wv; r < 128; r += 8){
            const float* er = enc + (size_t)r*160*1024;   // frame 0
            float a[8] = {0,0,0,0,0,0,0,0};
            #pragma unroll
            for (int c4 = 0; c4 < 4; ++c4){
                int k = c4*256 + lane*4;
                float4 ev = *(const float4*)(er + k);
                #pragma unroll
                for (int cc = 0; cc < 8; ++cc){
                    float4 w4 = *(const float4*)(sR + cc*1024 + k);
                    a[cc] += ev.x*w4.x + ev.y*w4.y + ev.z*w4.z + ev.w*w4.w;
                }
            }
            #pragma unroll
            for (int cc = 0; cc < 8; ++cc){
                #pragma unroll
                for (int off = 32; off; off >>= 1) a[cc] += __shfl_xor(a[cc], off, 64);
            }
            if (lane == 0){
                #pragma unroll
                for (int cc = 0; cc < 8; ++cc) encPT[(size_t)(cg0+cc)*128 + r] = a[cc];
            }
        }
    } else if (bid >= 240){
        int q = bid - 240;
        if (tid < 8){
            int r = q*8 + tid;
            actA[r] = 1; encTA[r] = 0; nEmA[r] = 0; scoresA[r] = 0.f;
        }
    }
    gsync(true);

    for (int s = 0; s < 48; ++s){
        const int p = s & 1, w = 1 - p;
        const float* hp = hT + (size_t)p*81920;
        float ai=0.f, af=0.f, ag=0.f, ao=0.f;   // LSTM gates live P1 -> P3 in registers

        // ================= P1: joint (+ fused LSTM pre-gates for blocks<160) =================
        if (bid < 160){
            int jj = wv >> 1, rh = wv & 1;
            int r = rh*64 + lane;
            const float* hc = hp + r;
            const float4* w4p = ((const float4*)sR) + jj*640;
            if (jj < 2){
                const float* wj = sA + jj*640;
                float aj = 0.f;
                #pragma unroll 8
                for (int k = 0; k < 640; ++k){
                    float h = hc[(size_t)k*128];
                    float4 w4 = w4p[k];
                    ai += h*w4.x; af += h*w4.y; ag += h*w4.z; ao += h*w4.w;
                    aj += h*wj[k];
                }
                int cg = bid*2 + jj;
                float v = aj + encPT[(size_t)cg*128 + r] + sBJ[jj];
                jointT[(size_t)cg*128 + r] = tanhf(v);
            } else {
                #pragma unroll 8
                for (int k = 0; k < 640; ++k){
                    float h = hc[(size_t)k*128];
                    float4 w4 = w4p[k];
                    ai += h*w4.x; af += h*w4.y; ag += h*w4.z; ao += h*w4.w;
                }
            }
        } else {
            int c = wv & 1, rh = (wv >> 1) & 1, kh = wv >> 2;
            int r = rh*64 + lane;
            const float* wr = sA + c*640 + kh*320;
            const float* hc = hp + (size_t)(kh*320)*128 + r;
            float acc = 0.f;
            #pragma unroll 16
            for (int k = 0; k < 320; ++k) acc += hc[(size_t)k*128] * wr[k];
            sXA[wv*64 + lane] = acc;
            __syncthreads();
            if (tid < 256){
                int c2 = wv & 1, rh2 = wv >> 1;
                int r2 = rh2*64 + lane;
                int cg = bid*2 + c2;
                float v = sXA[(c2 + rh2*2)*64 + lane] + sXA[(c2 + rh2*2 + 4)*64 + lane]
                        + encPT[(size_t)cg*128 + r2] + sBJ[c2];
                jointT[(size_t)cg*128 + r2] = tanhf(v);
            }
        }
        gsync(false);   // B1

        // ================= P2: logits + block argmax -> 16-slot atomics =================
        {
            int kq = wv >> 1, rh = wv & 1;
            int r = rh*64 + lane;
            const float* jc = jointT + (size_t)(kq*128)*128 + r;
            const float4* wb = sB4 + kq*128;
            float a0=0.f, a1=0.f, a2=0.f, a3=0.f;
            #pragma unroll 8
            for (int k = 0; k < 128; ++k){
                float jv = jc[(size_t)k*128];
                float4 w4 = wb[k];
                a0 += jv*w4.x; a1 += jv*w4.y; a2 += jv*w4.z; a3 += jv*w4.w;
            }
            sP[kq*512 + 0*128 + r] = a0;
            sP[kq*512 + 1*128 + r] = a1;
            sP[kq*512 + 2*128 + r] = a2;
            sP[kq*512 + 3*128 + r] = a3;
            __syncthreads();
            {
                int c = tid >> 7, rr = tid & 127;
                float lg = sP[c*128+rr] + sP[512 + c*128+rr] + sP[1024 + c*128+rr] + sP[1536 + c*128+rr];
                float ex = expf(lg);
                int col = bid*4 + c;
                bool force = nEmA[p*128 + rr] >= 2;
                int idx; float va;
                if (col == 0){ idx = 1024; va = lg; }
                else { idx = col; va = force ? LOWV : lg; }
                u64 key = ((u64)fkey(va) << 32) | (unsigned)(2047 - idx);
                sKX[c*128 + rr] = key;
                sEX[c*128 + rr] = ex;
            }
            __syncthreads();
            if (tid < 128){
                u64 m = sKX[tid]; float es = sEX[tid];
                #pragma unroll
                for (int q = 1; q < 4; ++q){
                    u64 o = sKX[q*128 + tid]; if (o > m) m = o;
                    es += sEX[q*128 + tid];
                }
                int slot = bid >> 4;
                atomicMax(&packed16[((size_t)s*16 + slot)*128 + tid], m);
                atomicAdd(&sumexp16[((size_t)s*16 + slot)*128 + tid], es);
            }
        }
        gsync(false);   // B2

        // ================= P2b: 16 reducer blocks finalize argmax + scalar state =================
        if (bid >= 240 && tid < 128){
            int q = bid - 240;
            int rr = q*8 + (tid >> 4), sl = tid & 15;
            u64 key = __hip_atomic_load(&packed16[((size_t)s*16 + sl)*128 + rr], __ATOMIC_RELAXED, __HIP_MEMORY_SCOPE_AGENT);
            float es = __hip_atomic_load(&sumexp16[((size_t)s*16 + sl)*128 + rr], __ATOMIC_RELAXED, __HIP_MEMORY_SCOPE_AGENT);
            #pragma unroll
            for (int off = 1; off < 16; off <<= 1){
                unsigned lo = __shfl_xor((unsigned)key, off, 64);
                unsigned hi = __shfl_xor((unsigned)(key >> 32), off, 64);
                u64 o = ((u64)hi << 32) | lo;
                if (o > key) key = o;
                es += __shfl_xor(es, off, 64);
            }
            if (sl == 0){
                int r = rr;
                int act = actA[p*128 + r];
                int et  = encTA[p*128 + r];
                int ne  = nEmA[p*128 + r];
                float sc = scoresA[p*128 + r];
                int len = lens[r];
                int tok_out = 1024, act_n = 0, tokF_v = -1, advF_v = -1;
                if (act){
                    int tok = 2047 - (int)(unsigned)(key & 0xffffffffu);
                    float chosen = funkey((unsigned)(key >> 32));
                    float tlp = chosen - logf(es);
                    int isb = (tok == 1024);
                    sc += tlp;
                    if (isb){ et += 1; ne = 0; } else { ne += 1; tokF_v = tok; }
                    act_n = (et < len) ? 1 : 0;
                    tok_out = (act_n || isb) ? tok : 1024;
                    if (isb && act_n) advF_v = et;   // et < len <= 160 -> et <= 159
                }
                actA[w*128 + r] = act_n;
                encTA[w*128 + r] = et;
                nEmA[w*128 + r]  = ne;
                scoresA[w*128 + r] = sc;
                tokF[w*128 + r] = tokF_v;
                advF[w*128 + r] = advF_v;
                out[(size_t)r*48 + s] = (float)tok_out;
                if (s == 47) out[6144 + r] = sc;
            }
        }
        gsync(false);   // B3

        // ================= P3: LSTM finalize | lazy encP =================
        if (bid < 160){
            int jj = wv >> 1, rh = wv & 1;
            int r = rh*64 + lane, j = bid*4 + jj;
            int tf = tokF[w*128 + r];
            float h2;
            if (tf >= 0){
                float4 ew = EWi4[(size_t)tf*640 + j];
                float cn = sigf(af + ew.y)*creg + sigf(ai + ew.x)*tanhf(ag + ew.z);
                h2 = tanhf(cn)*sigf(ao + ew.w);
                creg = cn;
            } else {
                h2 = hp[(size_t)j*128 + r];
            }
            hT[(size_t)w*81920 + (size_t)j*128 + r] = h2;
        } else if (bid < 224){
            int cg0 = (bid-160)*8;
            for (int r = wv; r < 128; r += 8){
                int t = advF[w*128 + r];
                if (t < 0) continue;
                const float* er = enc + ((size_t)r*160 + t)*1024;
                float a[8] = {0,0,0,0,0,0,0,0};
                #pragma unroll
                for (int c4 = 0; c4 < 4; ++c4){
                    int k = c4*256 + lane*4;
                    float4 ev = *(const float4*)(er + k);
                    #pragma unroll
                    for (int cc = 0; cc < 8; ++cc){
                        float4 w4 = *(const float4*)(sR + cc*1024 + k);
                        a[cc] += ev.x*w4.x + ev.y*w4.y + ev.z*w4.z + ev.w*w4.w;
                    }
                }
                #pragma unroll
                for (int cc = 0; cc < 8; ++cc){
                    #pragma unroll
                    for (int off = 32; off; off >>= 1) a[cc] += __shfl_xor(a[cc], off, 64);
                }
                if (lane == 0){
                    #pragma unroll
                    for (int cc = 0; cc < 8; ++cc) encPT[(size_t)(cg0+cc)*128 + r] = a[cc];
                }
            }
        }
        gsync(true);    // B4 (+inv for next step)
    }
}

extern "C" void kernel_launch(void* const* d_in, const int* in_sizes, int n_in,
                              void* d_out, int out_size, void* d_ws, size_t ws_size,
                              hipStream_t stream) {
    const float* enc   = (const float*)d_in[0];
    const int*   lens  = (const int*)  d_in[1];
    const float* E     = (const float*)d_in[3];
    const float* Wi    = (const float*)d_in[4];
    const float* Wh    = (const float*)d_in[5];
    const float* bi    = (const float*)d_in[6];
    const float* bh    = (const float*)d_in[7];
    const float* Wenc  = (const float*)d_in[8];
    const float* Wpred = (const float*)d_in[9];
    const float* bj    = (const float*)d_in[10];
    const float* Wout  = (const float*)d_in[11];
    float* out = (float*)d_out;

    char* base = (char*)d_ws;
    size_t off = 0;
    auto carve = [&](size_t bytes) -> void* {
        void* pp = base + off;
        off += (bytes + 255) & ~(size_t)255;
        return pp;
    };
    float4* Whx4  = (float4*)carve((size_t)640*640*16);
    float*  WpredT= (float*)carve((size_t)512*640*4);
    float*  WoutT = (float*)carve((size_t)1024*512*4);
    float*  WencT = (float*)carve((size_t)512*1024*4);
    float4* EWi4  = (float4*)carve((size_t)1024*640*16);
    float*  hT    = (float*)carve((size_t)2*640*128*4);
    float*  encPT = (float*)carve((size_t)512*128*4);
    float*  jointT= (float*)carve((size_t)512*128*4);
    u64*    packed16 = (u64*)carve((size_t)48*16*128*8);
    float*  sumexp16 = (float*)carve((size_t)48*16*128*4);
    int*    actA  = (int*)carve(2*128*4);
    int*    encTA = (int*)carve(2*128*4);
    int*    nEmA  = (int*)carve(2*128*4);
    float*  scoresA = (float*)carve(2*128*4);
    int*    tokF  = (int*)carve(2*128*4);
    int*    advF  = (int*)carve(2*128*4);
    int*    cnt32 = (int*)carve(32*16*4);
    (void)ws_size; (void)in_sizes; (void)n_in; (void)out_size;

    k_t0 <<<1600, 256, 0, stream>>>(Wh, Whx4, cnt32);
    k_tr <<<336,  256, 0, stream>>>(Wpred, Wout, Wenc, WpredT, WoutT, WencT);
    k_ewi<<<1280, 256, 0, stream>>>(E, Wi, bi, bh, EWi4);
    mega <<<NBLK, 512, 0, stream>>>(enc, lens, bj, WpredT, WoutT, WencT, Whx4, EWi4,
                                    hT, encPT, jointT, packed16, sumexp16,
                                    actA, encTA, nEmA, scoresA, tokF, advF, cnt32, out);
}